// Round 16
// baseline (149.492 us; speedup 1.0000x reference)
//
#include <hip/hip_runtime.h>
#include <hip/hip_bf16.h>

typedef unsigned short u16;
typedef __attribute__((ext_vector_type(8))) short bf16x8;
typedef __attribute__((ext_vector_type(8))) unsigned short u16x8;
typedef __attribute__((ext_vector_type(4))) float f32x4;

#define MFMA16(a,b,c) __builtin_amdgcn_mfma_f32_16x16x32_bf16(a,b,c,0,0,0)

__device__ __forceinline__ u16 f2bf(float f) {
  union { float f; unsigned int u; } v; v.f = f;
  unsigned int r = v.u + 0x7fffu + ((v.u >> 16) & 1u);  // RNE, finite inputs
  return (u16)(r >> 16);
}
__device__ __forceinline__ float bf2f(u16 u) {
  union { unsigned int i; float f; } v; v.i = ((unsigned int)u) << 16; return v.f;
}
__device__ __forceinline__ float exp2a(float x) {   // raw v_exp_f32 (args bounded)
  float r;
  asm("v_exp_f32 %0, %1" : "=v"(r) : "v"(x));
  return r;
}
__device__ __forceinline__ float max3(float a, float b, float c) {
  float r;
  asm("v_max3_f32 %0, %1, %2, %3" : "=v"(r) : "v"(a), "v"(b), "v"(c));
  return r;
}

__device__ __forceinline__ void gld16(const void* g, void* l) {
  __builtin_amdgcn_global_load_lds((const __attribute__((address_space(1))) void*)g,
                                   (__attribute__((address_space(3))) void*)l, 16, 0, 0);
}

// ---------------- fused prep: cast4 (blocks 0..6143) + ttrans qkv + ttrans proj ----------------
__device__ __forceinline__ void ttrans_body(const float* __restrict__ in, u16* __restrict__ out,
                                            int K, int N, int blk, int tid, u16 T[64][65]) {
  const int ntx = N >> 6;
  const int tx = blk % ntx, ty = blk / ntx;
  const int n0 = tx * 64, k0 = ty * 64;
  #pragma unroll
  for (int p = 0; p < 4; ++p) {
    int idx = p * 256 + tid;            // 0..1023
    int r = idx >> 4, ch = idx & 15;
    float4 v = *reinterpret_cast<const float4*>(in + (size_t)(k0 + r) * N + n0 + ch * 4);
    T[r][ch * 4 + 0] = f2bf(v.x);
    T[r][ch * 4 + 1] = f2bf(v.y);
    T[r][ch * 4 + 2] = f2bf(v.z);
    T[r][ch * 4 + 3] = f2bf(v.w);
  }
  __syncthreads();
  #pragma unroll
  for (int p = 0; p < 2; ++p) {
    int idx = p * 256 + tid;            // 0..511
    int rr = idx >> 3, ch = idx & 7;
    u16x8 o;
    #pragma unroll
    for (int e = 0; e < 8; ++e) o[e] = T[ch * 8 + e][rr];
    *reinterpret_cast<u16x8*>(out + (size_t)(n0 + rr) * K + k0 + ch * 8) = o;
  }
}

__global__ void prep(const float* __restrict__ hs, u16* __restrict__ hs_bf,
                     const float* __restrict__ qkv_w, u16* __restrict__ qkvwT,
                     const float* __restrict__ proj_w, u16* __restrict__ projwT) {
  __shared__ u16 T[64][65];
  const int blk = blockIdx.x, tid = threadIdx.x;
  if (blk < 6144) {
    int i = blk * 256 + tid;            // n4 = 1572864 = 6144*256 exact
    float4 v = reinterpret_cast<const float4*>(hs)[i];
    ushort4 o; o.x = f2bf(v.x); o.y = f2bf(v.y); o.z = f2bf(v.z); o.w = f2bf(v.w);
    reinterpret_cast<ushort4*>(hs_bf)[i] = o;
  } else if (blk < 6360) {
    ttrans_body(qkv_w, qkvwT, 384, 2304, blk - 6144, tid, T);
  } else {
    ttrans_body(proj_w, projwT, 768, 768, blk - 6360, tid, T);
  }
}

// ---------------- GEMM: C[M,N] = A[M,K] * Bt[N,K]^T + bias ----------------
// MT x 128 tile (MT=128 or 64), BK=32, dbuf LDS, counted-vmcnt prefetch, XCD swizzle.
template<int EPI, int MT>
__launch_bounds__(256)
__global__ void gemm_bt(const u16* __restrict__ A, const u16* __restrict__ Bt,
                        const float* __restrict__ bias,
                        u16* __restrict__ qp, u16* __restrict__ ok, u16* __restrict__ ov,
                        float* __restrict__ of, int K, int nbx, int cpx) {
  constexpr int ASZ = MT * 32;              // u16 per A buffer
  constexpr int MI = MT / 32;               // mi loop bound
  __shared__ __align__(16) u16 Sh[2 * ASZ + 8192];
  const int id = blockIdx.x;
  const int id2 = (id & 7) * cpx + (id >> 3);   // cpx = nwg/8
  const int bx = id2 % nbx, by = id2 / nbx;
  const int tid = threadIdx.x;
  const int wave = tid >> 6, lane = tid & 63;
  const int c = lane & 15, g = lane >> 4;
  const int brow = by * MT, bcol = bx * 128;
  const int wr = (wave >> 1) * (MT / 2), wc = (wave & 1) * 64;
  f32x4 acc[MI][4] = {};
  const int srow = (MT == 128) ? (wave * 32 + (lane >> 2)) : (wave * 16 + (lane >> 2));
  const int scol = (lane & 3) * 8;
  const u16* agp0 = A  + (size_t)(brow + srow) * K + scol;
  const u16* agp1 = A  + (size_t)(brow + srow + 16) * K + scol;   // MT==128 only
  const int bsrow = wave * 32 + (lane >> 2);
  const u16* bgp0 = Bt + (size_t)(bcol + bsrow) * K + scol;
  const u16* bgp1 = Bt + (size_t)(bcol + bsrow + 16) * K + scol;
  const int alo = (MT == 128) ? (wave * 1024) : (wave * 512);
  const int blo = 2 * ASZ + wave * 1024;
  const int nk = K >> 5;
  gld16(agp0, &Sh[alo]);
  if (MT == 128) gld16(agp1, &Sh[alo + 512]);
  gld16(bgp0, &Sh[blo]);
  gld16(bgp1, &Sh[blo + 512]);
  for (int ks = 0; ks < nk; ++ks) {
    const int cur = ks & 1;
    if (ks + 1 < nk) {
      const int k1 = (ks + 1) << 5;
      const int anb = (cur ^ 1) * ASZ;
      const int bnb = (cur ^ 1) * 4096;
      gld16(agp0 + k1, &Sh[anb + alo]);
      if (MT == 128) gld16(agp1 + k1, &Sh[anb + alo + 512]);
      gld16(bgp0 + k1, &Sh[blo + bnb]);
      gld16(bgp1 + k1, &Sh[blo + bnb + 512]);
      if (MT == 128) { asm volatile("s_waitcnt vmcnt(4)" ::: "memory"); }
      else           { asm volatile("s_waitcnt vmcnt(3)" ::: "memory"); }
    } else {
      asm volatile("s_waitcnt vmcnt(0)" ::: "memory");
    }
    __builtin_amdgcn_s_barrier();
    __builtin_amdgcn_sched_barrier(0);
    const int acb = cur * ASZ;
    const int bcb = 2 * ASZ + cur * 4096;
    bf16x8 af[MI], bfr[4];
    #pragma unroll
    for (int mi = 0; mi < MI; ++mi)
      af[mi] = *reinterpret_cast<const bf16x8*>(&Sh[acb + (wr + mi * 16 + c) * 32 + g * 8]);
    #pragma unroll
    for (int ni = 0; ni < 4; ++ni)
      bfr[ni] = *reinterpret_cast<const bf16x8*>(&Sh[bcb + (wc + ni * 16 + c) * 32 + g * 8]);
    #pragma unroll
    for (int mi = 0; mi < MI; ++mi)
      #pragma unroll
      for (int ni = 0; ni < 4; ++ni)
        acc[mi][ni] = MFMA16(af[mi], bfr[ni], acc[mi][ni]);
    __builtin_amdgcn_sched_barrier(0);
    __builtin_amdgcn_s_barrier();
  }
  if (EPI == 0 && MT == 128 && bcol < 768) {
    // ---- fused 2x2 maxpool ----
    const float SC = 0.14724744f;       // 96^-0.5 * log2(e)
    float* P = (float*)&Sh[0];          // [2][32][64] f32 = 16KB
    float m01[4][4], m23[4][4];
    #pragma unroll
    for (int mi = 0; mi < MI; ++mi)
      #pragma unroll
      for (int ni = 0; ni < 4; ++ni) {
        m01[mi][ni] = fmaxf(acc[mi][ni][0], acc[mi][ni][1]);
        m23[mi][ni] = fmaxf(acc[mi][ni][2], acc[mi][ni][3]);
      }
    if (wr == 64) {
      #pragma unroll
      for (int mi = 0; mi < MI; ++mi)
        #pragma unroll
        for (int ni = 0; ni < 4; ++ni) {
          const int pw = mi * 8 + g * 2;
          P[(wave & 1) * 2048 + pw * 64 + ni * 16 + c]       = m01[mi][ni];
          P[(wave & 1) * 2048 + (pw + 1) * 64 + ni * 16 + c] = m23[mi][ni];
        }
    }
    __syncthreads();
    if (wr == 0) {
      const int b = brow >> 12;
      const int hq = (brow >> 7) & 31;
      const size_t rbase = (size_t)(b * 1024 + hq * 32);
      #pragma unroll
      for (int mi = 0; mi < MI; ++mi)
        #pragma unroll
        for (int ni = 0; ni < 4; ++ni) {
          const int col = bcol + wc + ni * 16 + c;
          const float bz = bias[col];
          const int pw = mi * 8 + g * 2;
          float v0 = fmaxf(m01[mi][ni], P[(wave & 1) * 2048 + pw * 64 + ni * 16 + c]);
          float v1 = fmaxf(m23[mi][ni], P[(wave & 1) * 2048 + (pw + 1) * 64 + ni * 16 + c]);
          qp[(rbase + pw) * 768 + col]     = f2bf((v0 + bz) * SC);
          qp[(rbase + pw + 1) * 768 + col] = f2bf((v1 + bz) * SC);
        }
    }
    return;
  }
  if (EPI == 0 && MT == 128 && bcol >= 1536) {
    // ---- V epilogue: in-LDS transpose -> vT with per-64-tile key permutation ----
    u16* T = &Sh[0];
    const int vc0 = bcol - 1536;
    const int bq = brow >> 12;
    const int s0 = brow & 4095;
    #pragma unroll
    for (int ni = 0; ni < 4; ++ni) {
      const int j = wc + ni * 16 + c;
      const float bz = bias[bcol + j];
      const int key = (j & 15) << 2;
      #pragma unroll
      for (int mi = 0; mi < MI; ++mi) {
        const int rb = wr + mi * 16 + g * 4;
        ushort4 o;
        o.x = f2bf(acc[mi][ni][0] + bz);
        o.y = f2bf(acc[mi][ni][1] + bz);
        o.z = f2bf(acc[mi][ni][2] + bz);
        o.w = f2bf(acc[mi][ni][3] + bz);
        *reinterpret_cast<ushort4*>(&T[j * 128 + (rb ^ key)]) = o;
      }
    }
    __syncthreads();
    u16* vb2 = ov + ((size_t)(bq * 768 + vc0)) * 4096 + s0;
    #pragma unroll
    for (int p = 0; p < 8; ++p) {
      const int j = p * 16 + wave * 4 + (lane >> 4);
      const int sc = lane & 15;
      const int key = j & 15;
      const int p4 = 8 * (sc >> 3) + 2 * (sc & 3) + ((sc >> 2) & 1);
      uint2 lo = *reinterpret_cast<uint2*>(&T[j * 128 + ((sc ^ key) << 2)]);
      uint2 hi = *reinterpret_cast<uint2*>(&T[j * 128 + (((sc + 16) ^ key) << 2)]);
      *reinterpret_cast<uint2*>(vb2 + (size_t)j * 4096 + p4 * 4)      = lo;
      *reinterpret_cast<uint2*>(vb2 + (size_t)j * 4096 + 64 + p4 * 4) = hi;
    }
    return;
  }
  #pragma unroll
  for (int mi = 0; mi < MI; ++mi) {
    #pragma unroll
    for (int ni = 0; ni < 4; ++ni) {
      const int col = bcol + wc + ni * 16 + c;
      const float bz = bias[col];
      #pragma unroll
      for (int i = 0; i < 4; ++i) {
        const int row = brow + wr + mi * 16 + g * 4 + i;
        float v = acc[mi][ni][i] + bz;
        if (EPI == 0) {
          ok[(size_t)row * 768 + col - 768] = f2bf(v);
        } else {
          of[(size_t)row * 768 + col] = v;
        }
      }
    }
  }
}

// ---------------- flash attention: K-dbuf + counted-vmcnt pipeline, in-block split+combine ----------------
// grid 512, XCD remap. Per sq (u16 idx base sq*18432): K0@+0, K1@+6144, V@+12288. 72KB total.
// K(kt+1) prefetched a full iteration ahead (dbuf); V(kt) issued at phase top, consumed
// after QK^T+softmax+pack (~600cy flight). vmcnt(6) retires K(kt); vmcnt(3) retires V(kt).
// kt=31's K(32) junk prefetch lands in the spare ws region; drained before Cb overlay.
__launch_bounds__(512, 4)
__global__ void flash11(const u16* __restrict__ Qp, const u16* __restrict__ Kb,
                        const u16* __restrict__ Vtg, u16* __restrict__ aout) {
  const int blk = blockIdx.x;
  const int xcd = blk & 7, j = blk >> 3;
  const int bh = xcd + 8 * (j >> 4), qt = j & 15;
  const int b = bh >> 3, h = bh & 7;
  __shared__ __align__(16) u16 Sh[36864];
  const int tid = threadIdx.x, w = tid >> 6, lane = tid & 63;
  const int sq = w >> 2, wq = w & 3;
  const int c = lane & 15, g = lane >> 4;
  const int sbase = sq * 18432;
  const int vbase = sbase + 12288;
  const u16* qb = Qp + ((size_t)(b * 1024 + qt * 64 + wq * 16 + c)) * 768 + h * 96;
  bf16x8 qf[3];
  #pragma unroll
  for (int kc = 0; kc < 3; ++kc)
    qf[kc] = *reinterpret_cast<const bf16x8*>(qb + kc * 32 + g * 8);
  const u16* kp[3];
  const u16* vp[3];
  int loff[3];
  {
    const u16* kb0 = Kb + ((size_t)(b * 4096 + sq * 2048)) * 768 + h * 96;
    const u16* vb0 = Vtg + ((size_t)(bh * 96)) * 4096 + sq * 2048;
    #pragma unroll
    for (int j2 = 0; j2 < 3; ++j2) {
      int p = wq * 192 + j2 * 64 + lane;  // 0..767
      int r = p / 12, ch = p - r * 12;
      kp[j2] = kb0 + r * 768 + ch * 8;
      int d = p >> 3, vch = p & 7;
      vp[j2] = vb0 + d * 4096 + ((vch ^ (d & 7)) * 8);
      loff[j2] = (wq * 192 + j2 * 64) * 8;
    }
  }
  asm volatile("s_waitcnt vmcnt(0)" ::: "memory");  // Q landed; clean vmem ledger
  // prologue: K(0) into K-buffer 0
  #pragma unroll
  for (int j2 = 0; j2 < 3; ++j2) gld16(kp[j2], &Sh[sbase + loff[j2]]);
  #pragma unroll
  for (int j2 = 0; j2 < 3; ++j2) kp[j2] += 49152;
  float m = -1e30f, l = 0.f;
  f32x4 acc[6] = {};
  const f32x4 z4 = {0.f, 0.f, 0.f, 0.f};
  const int sw = (c & 7) << 3;
  for (int kt = 0; kt < 32; ++kt) {
    const int cur = kt & 1;
    // issue V(kt) then K(kt+1) (into the other K buffer)
    #pragma unroll
    for (int j2 = 0; j2 < 3; ++j2) gld16(vp[j2], &Sh[vbase + loff[j2]]);
    #pragma unroll
    for (int j2 = 0; j2 < 3; ++j2) gld16(kp[j2], &Sh[sbase + (cur ^ 1) * 6144 + loff[j2]]);
    #pragma unroll
    for (int j2 = 0; j2 < 3; ++j2) { vp[j2] += 64; kp[j2] += 49152; }
    __builtin_amdgcn_sched_barrier(0);
    asm volatile("s_waitcnt vmcnt(6)" ::: "memory");   // K(kt) landed (oldest 3 retired)
    __builtin_amdgcn_s_barrier();                       // all waves' K(kt) visible
    __builtin_amdgcn_sched_barrier(0);
    // swapped QK^T from K[cur]; first MFMA uses C=0
    const int kb2 = sbase + cur * 6144;
    f32x4 st[4];
    __builtin_amdgcn_s_setprio(1);
    #pragma unroll
    for (int kt4 = 0; kt4 < 4; ++kt4) {
      bf16x8 kf = *reinterpret_cast<const bf16x8*>(&Sh[kb2 + (kt4 * 16 + c) * 96 + g * 8]);
      st[kt4] = MFMA16(kf, qf[0], z4);
    }
    #pragma unroll
    for (int kc = 1; kc < 3; ++kc)
      #pragma unroll
      for (int kt4 = 0; kt4 < 4; ++kt4) {
        bf16x8 kf = *reinterpret_cast<const bf16x8*>(&Sh[kb2 + (kt4 * 16 + c) * 96 + kc * 32 + g * 8]);
        st[kt4] = MFMA16(kf, qf[kc], st[kt4]);
      }
    __builtin_amdgcn_s_setprio(0);
    // row max: max3 tree + 2 shfl
    float pmax;
    {
      float a0 = max3(st[0][0], st[0][1], st[0][2]);
      float a1 = max3(st[0][3], st[1][0], st[1][1]);
      float a2 = max3(st[1][2], st[1][3], st[2][0]);
      float a3 = max3(st[2][1], st[2][2], st[2][3]);
      float a4 = max3(st[3][0], st[3][1], st[3][2]);
      pmax = fmaxf(max3(a0, a1, st[3][3]), max3(a2, a3, a4));
    }
    pmax = fmaxf(pmax, __shfl_xor(pmax, 16));
    pmax = fmaxf(pmax, __shfl_xor(pmax, 32));
    if (__any(pmax > m + 8.0f)) {
      float mn = fmaxf(m, pmax);
      float esc = exp2a(m - mn);
      m = mn;
      l *= esc;
      float er[4];
      #pragma unroll
      for (int i = 0; i < 4; ++i) er[i] = __shfl(esc, g * 4 + i);
      #pragma unroll
      for (int dc = 0; dc < 6; ++dc)
        #pragma unroll
        for (int i = 0; i < 4; ++i)
          acc[dc][i] *= er[i];
    }
    float ps = 0.f;
    #pragma unroll
    for (int kt4 = 0; kt4 < 4; ++kt4)
      #pragma unroll
      for (int i = 0; i < 4; ++i) {
        float p = exp2a(st[kt4][i] - m);
        st[kt4][i] = p;
        ps += p;
      }
    ps += __shfl_xor(ps, 16);
    ps += __shfl_xor(ps, 32);
    l += ps;
    // pack P in-lane (vT key permutation makes PV A-frag in-lane)
    unsigned int uu[4][2];
    #pragma unroll
    for (int kt4 = 0; kt4 < 4; ++kt4) {
      asm("v_cvt_pk_bf16_f32 %0, %1, %2" : "=v"(uu[kt4][0]) : "v"(st[kt4][0]), "v"(st[kt4][1]));
      asm("v_cvt_pk_bf16_f32 %0, %1, %2" : "=v"(uu[kt4][1]) : "v"(st[kt4][2]), "v"(st[kt4][3]));
    }
    __builtin_amdgcn_sched_barrier(0);
    asm volatile("s_waitcnt vmcnt(3)" ::: "memory");   // V(kt) landed (K(kt+1) stays in flight)
    __builtin_amdgcn_s_barrier();                       // all waves' V visible
    __builtin_amdgcn_sched_barrier(0);
    // PV
    __builtin_amdgcn_s_setprio(1);
    #pragma unroll
    for (int kh = 0; kh < 2; ++kh) {
      union { unsigned int wrd[4]; bf16x8 v; } pfu;
      pfu.wrd[0] = uu[2 * kh][0];
      pfu.wrd[1] = uu[2 * kh][1];
      pfu.wrd[2] = uu[2 * kh + 1][0];
      pfu.wrd[3] = uu[2 * kh + 1][1];
      bf16x8 pf = pfu.v;
      #pragma unroll
      for (int dc = 0; dc < 6; ++dc) {
        bf16x8 vf = *reinterpret_cast<const bf16x8*>(&Sh[vbase + (dc * 16 + c) * 64 + ((kh * 32 + g * 8) ^ sw)]);
        acc[dc] = MFMA16(pf, vf, acc[dc]);
      }
    }
    __builtin_amdgcn_s_setprio(0);
    __builtin_amdgcn_sched_barrier(0);
    __builtin_amdgcn_s_barrier();                       // tail: phase kt fully done
  }
  // ---- in-block combine of the two key-halves ----
  __syncthreads();                       // full drain incl. K(32) junk prefetch
  float* Cb = (float*)&Sh[0];            // [4][16][96] f32 = 24KB (overlays sq0 K0/K1)
  float* Ml = (float*)&Sh[12288];        // [4][16][2] f32 (inside sq0 V region)
  if (sq == 1) {
    #pragma unroll
    for (int dc = 0; dc < 6; ++dc)
      #pragma unroll
      for (int i = 0; i < 4; ++i)
        Cb[(wq * 16 + g * 4 + i) * 96 + dc * 16 + c] = acc[dc][i];
    if (lane < 16) {
      Ml[(wq * 16 + lane) * 2]     = m;
      Ml[(wq * 16 + lane) * 2 + 1] = l;
    }
  }
  __syncthreads();
  if (sq == 0) {
    u16* ob = aout + (size_t)(b * 1024 + qt * 64 + wq * 16) * 768 + h * 96;
    #pragma unroll
    for (int i = 0; i < 4; ++i) {
      const int q = g * 4 + i;
      float m0q = __shfl(m, q), l0q = __shfl(l, q);
      float m1q = Ml[(wq * 16 + q) * 2], l1q = Ml[(wq * 16 + q) * 2 + 1];
      float M = fmaxf(m0q, m1q);
      float e0 = exp2a(m0q - M), e1 = exp2a(m1q - M);
      float inv = 1.f / (l0q * e0 + l1q * e1);
      #pragma unroll
      for (int dc = 0; dc < 6; ++dc) {
        float a1 = Cb[(wq * 16 + q) * 96 + dc * 16 + c];
        ob[(size_t)q * 768 + dc * 16 + c] = f2bf((acc[dc][i] * e0 + a1 * e1) * inv);
      }
    }
  }
}

extern "C" void kernel_launch(void* const* d_in, const int* in_sizes, int n_in,
                              void* d_out, int out_size, void* d_ws, size_t ws_size,
                              hipStream_t stream) {
  const float* hs     = (const float*)d_in[0];
  const float* qkv_w  = (const float*)d_in[1];
  const float* qkv_b  = (const float*)d_in[2];
  const float* proj_w = (const float*)d_in[3];
  const float* proj_b = (const float*)d_in[4];
  float* out = (float*)d_out;

  u16* hs_bf  = (u16*)d_ws;                 // 6291456 u16
  u16* qkvwT  = hs_bf  + 6291456;           // 884736
  u16* projwT = qkvwT  + 884736;            // 589824
  u16* vT     = projwT + 589824;            // 12582912 (32*96*4096)
  u16* kbuf   = vT     + 12582912;          // 12582912
  u16* spare  = kbuf   + 12582912;          // 12582912 (K(32) junk landing zone)
  u16* qpol   = spare  + 12582912;          // 3145728
  u16* aout   = qpol   + 3145728;           // 3145728

  prep<<<6504, 256, 0, stream>>>(hs, hs_bf, qkv_w, qkvwT, proj_w, projwT);

  gemm_bt<0, 128><<<2304, 256, 0, stream>>>(hs_bf, qkvwT, qkv_b,
                                            qpol, kbuf, vT, nullptr, 384, 18, 288);
  flash11<<<512, 512, 0, stream>>>(qpol, kbuf, vT, aout);
  gemm_bt<1, 64><<<384, 256, 0, stream>>>(aout, projwT, proj_b,
                                          nullptr, nullptr, nullptr, out, 768, 6, 48);
}

// Round 17
// 144.639 us; speedup vs baseline: 1.0336x; 1.0336x over previous
//
#include <hip/hip_runtime.h>
#include <hip/hip_bf16.h>

typedef unsigned short u16;
typedef __attribute__((ext_vector_type(8))) short bf16x8;
typedef __attribute__((ext_vector_type(8))) unsigned short u16x8;
typedef __attribute__((ext_vector_type(4))) float f32x4;

#define MFMA16(a,b,c) __builtin_amdgcn_mfma_f32_16x16x32_bf16(a,b,c,0,0,0)

__device__ __forceinline__ u16 f2bf(float f) {
  union { float f; unsigned int u; } v; v.f = f;
  unsigned int r = v.u + 0x7fffu + ((v.u >> 16) & 1u);  // RNE, finite inputs
  return (u16)(r >> 16);
}
__device__ __forceinline__ float bf2f(u16 u) {
  union { unsigned int i; float f; } v; v.i = ((unsigned int)u) << 16; return v.f;
}
__device__ __forceinline__ float exp2a(float x) {   // raw v_exp_f32 (args bounded)
  float r;
  asm("v_exp_f32 %0, %1" : "=v"(r) : "v"(x));
  return r;
}
__device__ __forceinline__ float max3(float a, float b, float c) {
  float r;
  asm("v_max3_f32 %0, %1, %2, %3" : "=v"(r) : "v"(a), "v"(b), "v"(c));
  return r;
}

__device__ __forceinline__ void gld16(const void* g, void* l) {
  __builtin_amdgcn_global_load_lds((const __attribute__((address_space(1))) void*)g,
                                   (__attribute__((address_space(3))) void*)l, 16, 0, 0);
}

// ---------------- fused prep: cast4 (blocks 0..6143) + ttrans qkv + ttrans proj ----------------
__device__ __forceinline__ void ttrans_body(const float* __restrict__ in, u16* __restrict__ out,
                                            int K, int N, int blk, int tid, u16 T[64][65]) {
  const int ntx = N >> 6;
  const int tx = blk % ntx, ty = blk / ntx;
  const int n0 = tx * 64, k0 = ty * 64;
  #pragma unroll
  for (int p = 0; p < 4; ++p) {
    int idx = p * 256 + tid;            // 0..1023
    int r = idx >> 4, ch = idx & 15;
    float4 v = *reinterpret_cast<const float4*>(in + (size_t)(k0 + r) * N + n0 + ch * 4);
    T[r][ch * 4 + 0] = f2bf(v.x);
    T[r][ch * 4 + 1] = f2bf(v.y);
    T[r][ch * 4 + 2] = f2bf(v.z);
    T[r][ch * 4 + 3] = f2bf(v.w);
  }
  __syncthreads();
  #pragma unroll
  for (int p = 0; p < 2; ++p) {
    int idx = p * 256 + tid;            // 0..511
    int rr = idx >> 3, ch = idx & 7;
    u16x8 o;
    #pragma unroll
    for (int e = 0; e < 8; ++e) o[e] = T[ch * 8 + e][rr];
    *reinterpret_cast<u16x8*>(out + (size_t)(n0 + rr) * K + k0 + ch * 8) = o;
  }
}

__global__ void prep(const float* __restrict__ hs, u16* __restrict__ hs_bf,
                     const float* __restrict__ qkv_w, u16* __restrict__ qkvwT,
                     const float* __restrict__ proj_w, u16* __restrict__ projwT) {
  __shared__ u16 T[64][65];
  const int blk = blockIdx.x, tid = threadIdx.x;
  if (blk < 6144) {
    int i = blk * 256 + tid;            // n4 = 1572864 = 6144*256 exact
    float4 v = reinterpret_cast<const float4*>(hs)[i];
    ushort4 o; o.x = f2bf(v.x); o.y = f2bf(v.y); o.z = f2bf(v.z); o.w = f2bf(v.w);
    reinterpret_cast<ushort4*>(hs_bf)[i] = o;
  } else if (blk < 6360) {
    ttrans_body(qkv_w, qkvwT, 384, 2304, blk - 6144, tid, T);
  } else {
    ttrans_body(proj_w, projwT, 768, 768, blk - 6360, tid, T);
  }
}

// ---------------- GEMM: C[M,N] = A[M,K] * Bt[N,K]^T + bias ----------------
// MT x 128 tile (MT=128 or 64), BK=32, dbuf LDS, counted-vmcnt prefetch, XCD swizzle.
// EPI 0 (MT=128 only): q cols -> fused maxpool -> qp; k cols -> kbuf; v cols -> vT (permuted).
// EPI 1: fp32 out (proj), MT=64 -> 384 blocks for full CU coverage.
template<int EPI, int MT>
__launch_bounds__(256)
__global__ void gemm_bt(const u16* __restrict__ A, const u16* __restrict__ Bt,
                        const float* __restrict__ bias,
                        u16* __restrict__ qp, u16* __restrict__ ok, u16* __restrict__ ov,
                        float* __restrict__ of, int K, int nbx, int cpx) {
  constexpr int ASZ = MT * 32;              // u16 per A buffer
  constexpr int MI = MT / 32;               // mi loop bound
  __shared__ __align__(16) u16 Sh[2 * ASZ + 8192];
  const int id = blockIdx.x;
  const int id2 = (id & 7) * cpx + (id >> 3);   // cpx = nwg/8
  const int bx = id2 % nbx, by = id2 / nbx;
  const int tid = threadIdx.x;
  const int wave = tid >> 6, lane = tid & 63;
  const int c = lane & 15, g = lane >> 4;
  const int brow = by * MT, bcol = bx * 128;
  const int wr = (wave >> 1) * (MT / 2), wc = (wave & 1) * 64;
  f32x4 acc[MI][4] = {};
  const int srow = (MT == 128) ? (wave * 32 + (lane >> 2)) : (wave * 16 + (lane >> 2));
  const int scol = (lane & 3) * 8;
  const u16* agp0 = A  + (size_t)(brow + srow) * K + scol;
  const u16* agp1 = A  + (size_t)(brow + srow + 16) * K + scol;   // MT==128 only
  const int bsrow = wave * 32 + (lane >> 2);
  const u16* bgp0 = Bt + (size_t)(bcol + bsrow) * K + scol;
  const u16* bgp1 = Bt + (size_t)(bcol + bsrow + 16) * K + scol;
  const int alo = (MT == 128) ? (wave * 1024) : (wave * 512);
  const int blo = 2 * ASZ + wave * 1024;
  const int nk = K >> 5;
  gld16(agp0, &Sh[alo]);
  if (MT == 128) gld16(agp1, &Sh[alo + 512]);
  gld16(bgp0, &Sh[blo]);
  gld16(bgp1, &Sh[blo + 512]);
  for (int ks = 0; ks < nk; ++ks) {
    const int cur = ks & 1;
    if (ks + 1 < nk) {
      const int k1 = (ks + 1) << 5;
      const int anb = (cur ^ 1) * ASZ;
      const int bnb = (cur ^ 1) * 4096;
      gld16(agp0 + k1, &Sh[anb + alo]);
      if (MT == 128) gld16(agp1 + k1, &Sh[anb + alo + 512]);
      gld16(bgp0 + k1, &Sh[blo + bnb]);
      gld16(bgp1 + k1, &Sh[blo + bnb + 512]);
      if (MT == 128) { asm volatile("s_waitcnt vmcnt(4)" ::: "memory"); }
      else           { asm volatile("s_waitcnt vmcnt(3)" ::: "memory"); }
    } else {
      asm volatile("s_waitcnt vmcnt(0)" ::: "memory");
    }
    __builtin_amdgcn_s_barrier();
    __builtin_amdgcn_sched_barrier(0);
    const int acb = cur * ASZ;
    const int bcb = 2 * ASZ + cur * 4096;
    bf16x8 af[MI], bfr[4];
    #pragma unroll
    for (int mi = 0; mi < MI; ++mi)
      af[mi] = *reinterpret_cast<const bf16x8*>(&Sh[acb + (wr + mi * 16 + c) * 32 + g * 8]);
    #pragma unroll
    for (int ni = 0; ni < 4; ++ni)
      bfr[ni] = *reinterpret_cast<const bf16x8*>(&Sh[bcb + (wc + ni * 16 + c) * 32 + g * 8]);
    #pragma unroll
    for (int mi = 0; mi < MI; ++mi)
      #pragma unroll
      for (int ni = 0; ni < 4; ++ni)
        acc[mi][ni] = MFMA16(af[mi], bfr[ni], acc[mi][ni]);
    __builtin_amdgcn_sched_barrier(0);
    __builtin_amdgcn_s_barrier();
  }
  if (EPI == 0 && MT == 128 && bcol < 768) {
    // ---- fused 2x2 maxpool ----
    const float SC = 0.14724744f;       // 96^-0.5 * log2(e)
    float* P = (float*)&Sh[0];          // [2][32][64] f32 = 16KB
    float m01[4][4], m23[4][4];
    #pragma unroll
    for (int mi = 0; mi < MI; ++mi)
      #pragma unroll
      for (int ni = 0; ni < 4; ++ni) {
        m01[mi][ni] = fmaxf(acc[mi][ni][0], acc[mi][ni][1]);
        m23[mi][ni] = fmaxf(acc[mi][ni][2], acc[mi][ni][3]);
      }
    if (wr == 64) {
      #pragma unroll
      for (int mi = 0; mi < MI; ++mi)
        #pragma unroll
        for (int ni = 0; ni < 4; ++ni) {
          const int pw = mi * 8 + g * 2;
          P[(wave & 1) * 2048 + pw * 64 + ni * 16 + c]       = m01[mi][ni];
          P[(wave & 1) * 2048 + (pw + 1) * 64 + ni * 16 + c] = m23[mi][ni];
        }
    }
    __syncthreads();
    if (wr == 0) {
      const int b = brow >> 12;
      const int hq = (brow >> 7) & 31;
      const size_t rbase = (size_t)(b * 1024 + hq * 32);
      #pragma unroll
      for (int mi = 0; mi < MI; ++mi)
        #pragma unroll
        for (int ni = 0; ni < 4; ++ni) {
          const int col = bcol + wc + ni * 16 + c;
          const float bz = bias[col];
          const int pw = mi * 8 + g * 2;
          float v0 = fmaxf(m01[mi][ni], P[(wave & 1) * 2048 + pw * 64 + ni * 16 + c]);
          float v1 = fmaxf(m23[mi][ni], P[(wave & 1) * 2048 + (pw + 1) * 64 + ni * 16 + c]);
          qp[(rbase + pw) * 768 + col]     = f2bf((v0 + bz) * SC);
          qp[(rbase + pw + 1) * 768 + col] = f2bf((v1 + bz) * SC);
        }
    }
    return;
  }
  if (EPI == 0 && MT == 128 && bcol >= 1536) {
    // ---- V epilogue: in-LDS transpose -> vT with per-64-tile key permutation ----
    u16* T = &Sh[0];
    const int vc0 = bcol - 1536;
    const int bq = brow >> 12;
    const int s0 = brow & 4095;
    #pragma unroll
    for (int ni = 0; ni < 4; ++ni) {
      const int j = wc + ni * 16 + c;
      const float bz = bias[bcol + j];
      const int key = (j & 15) << 2;
      #pragma unroll
      for (int mi = 0; mi < MI; ++mi) {
        const int rb = wr + mi * 16 + g * 4;
        ushort4 o;
        o.x = f2bf(acc[mi][ni][0] + bz);
        o.y = f2bf(acc[mi][ni][1] + bz);
        o.z = f2bf(acc[mi][ni][2] + bz);
        o.w = f2bf(acc[mi][ni][3] + bz);
        *reinterpret_cast<ushort4*>(&T[j * 128 + (rb ^ key)]) = o;
      }
    }
    __syncthreads();
    u16* vb2 = ov + ((size_t)(bq * 768 + vc0)) * 4096 + s0;
    #pragma unroll
    for (int p = 0; p < 8; ++p) {
      const int j = p * 16 + wave * 4 + (lane >> 4);
      const int sc = lane & 15;
      const int key = j & 15;
      const int p4 = 8 * (sc >> 3) + 2 * (sc & 3) + ((sc >> 2) & 1);
      uint2 lo = *reinterpret_cast<uint2*>(&T[j * 128 + ((sc ^ key) << 2)]);
      uint2 hi = *reinterpret_cast<uint2*>(&T[j * 128 + (((sc + 16) ^ key) << 2)]);
      *reinterpret_cast<uint2*>(vb2 + (size_t)j * 4096 + p4 * 4)      = lo;
      *reinterpret_cast<uint2*>(vb2 + (size_t)j * 4096 + 64 + p4 * 4) = hi;
    }
    return;
  }
  #pragma unroll
  for (int mi = 0; mi < MI; ++mi) {
    #pragma unroll
    for (int ni = 0; ni < 4; ++ni) {
      const int col = bcol + wc + ni * 16 + c;
      const float bz = bias[col];
      #pragma unroll
      for (int i = 0; i < 4; ++i) {
        const int row = brow + wr + mi * 16 + g * 4 + i;
        float v = acc[mi][ni][i] + bz;
        if (EPI == 0) {
          ok[(size_t)row * 768 + col - 768] = f2bf(v);
        } else {
          of[(size_t)row * 768 + col] = v;
        }
      }
    }
  }
}

// ---------------- flash attention (flash8, validated floor): 8 waves, in-block split+combine ----------------
// grid 512, XCD remap. Zero-LDS P transport (vT key permutation); VALU-diet softmax.
// LDS 48KB: K0@0, V0@6144, K1@12288, V1@18432 (u16 idx).
__launch_bounds__(512, 4)
__global__ void flash8(const u16* __restrict__ Qp, const u16* __restrict__ Kb,
                       const u16* __restrict__ Vtg, u16* __restrict__ aout) {
  const int blk = blockIdx.x;
  const int xcd = blk & 7, j = blk >> 3;
  const int bh = xcd + 8 * (j >> 4), qt = j & 15;
  const int b = bh >> 3, h = bh & 7;
  __shared__ __align__(16) u16 Sh[24576];
  const int tid = threadIdx.x, w = tid >> 6, lane = tid & 63;
  const int sq = w >> 2, wq = w & 3;
  const int c = lane & 15, g = lane >> 4;
  const int kbase = sq * 12288;
  const int vbase = 6144 + sq * 12288;
  const u16* qb = Qp + ((size_t)(b * 1024 + qt * 64 + wq * 16 + c)) * 768 + h * 96;
  bf16x8 qf[3];
  #pragma unroll
  for (int kc = 0; kc < 3; ++kc)
    qf[kc] = *reinterpret_cast<const bf16x8*>(qb + kc * 32 + g * 8);
  const u16* kp[3];
  const u16* vp[3];
  int loff[3];
  {
    const u16* kb0 = Kb + ((size_t)(b * 4096 + sq * 2048)) * 768 + h * 96;
    const u16* vb0 = Vtg + ((size_t)(bh * 96)) * 4096 + sq * 2048;
    #pragma unroll
    for (int j2 = 0; j2 < 3; ++j2) {
      int p = wq * 192 + j2 * 64 + lane;  // 0..767
      int r = p / 12, ch = p - r * 12;
      kp[j2] = kb0 + r * 768 + ch * 8;
      int d = p >> 3, vch = p & 7;
      vp[j2] = vb0 + d * 4096 + ((vch ^ (d & 7)) * 8);
      loff[j2] = (wq * 192 + j2 * 64) * 8;
    }
  }
  float m = -1e30f, l = 0.f;
  f32x4 acc[6] = {};
  const f32x4 z4 = {0.f, 0.f, 0.f, 0.f};
  const int sw = (c & 7) << 3;
  for (int kt = 0; kt < 32; ++kt) {
    __syncthreads();
    #pragma unroll
    for (int j2 = 0; j2 < 3; ++j2) gld16(kp[j2], &Sh[kbase + loff[j2]]);
    #pragma unroll
    for (int j2 = 0; j2 < 3; ++j2) gld16(vp[j2], &Sh[vbase + loff[j2]]);
    #pragma unroll
    for (int j2 = 0; j2 < 3; ++j2) { kp[j2] += 49152; vp[j2] += 64; }
    __syncthreads();
    // swapped QK^T; first MFMA uses C=0 (no zero-fill moves)
    f32x4 st[4];
    __builtin_amdgcn_s_setprio(1);
    #pragma unroll
    for (int kt4 = 0; kt4 < 4; ++kt4) {
      bf16x8 kf = *reinterpret_cast<const bf16x8*>(&Sh[kbase + (kt4 * 16 + c) * 96 + g * 8]);
      st[kt4] = MFMA16(kf, qf[0], z4);
    }
    #pragma unroll
    for (int kc = 1; kc < 3; ++kc)
      #pragma unroll
      for (int kt4 = 0; kt4 < 4; ++kt4) {
        bf16x8 kf = *reinterpret_cast<const bf16x8*>(&Sh[kbase + (kt4 * 16 + c) * 96 + kc * 32 + g * 8]);
        st[kt4] = MFMA16(kf, qf[kc], st[kt4]);
      }
    __builtin_amdgcn_s_setprio(0);
    // row max: max3 tree (8 inst) + 2 shfl
    float pmax;
    {
      float a0 = max3(st[0][0], st[0][1], st[0][2]);
      float a1 = max3(st[0][3], st[1][0], st[1][1]);
      float a2 = max3(st[1][2], st[1][3], st[2][0]);
      float a3 = max3(st[2][1], st[2][2], st[2][3]);
      float a4 = max3(st[3][0], st[3][1], st[3][2]);
      pmax = fmaxf(max3(a0, a1, st[3][3]), max3(a2, a3, a4));
    }
    pmax = fmaxf(pmax, __shfl_xor(pmax, 16));
    pmax = fmaxf(pmax, __shfl_xor(pmax, 32));
    if (__any(pmax > m + 8.0f)) {
      float mn = fmaxf(m, pmax);
      float esc = exp2a(m - mn);
      m = mn;
      l *= esc;
      float er[4];
      #pragma unroll
      for (int i = 0; i < 4; ++i) er[i] = __shfl(esc, g * 4 + i);
      #pragma unroll
      for (int dc = 0; dc < 6; ++dc)
        #pragma unroll
        for (int i = 0; i < 4; ++i)
          acc[dc][i] *= er[i];
    }
    float ps = 0.f;
    #pragma unroll
    for (int kt4 = 0; kt4 < 4; ++kt4)
      #pragma unroll
      for (int i = 0; i < 4; ++i) {
        float p = exp2a(st[kt4][i] - m);
        st[kt4][i] = p;
        ps += p;
      }
    ps += __shfl_xor(ps, 16);
    ps += __shfl_xor(ps, 32);
    l += ps;
    // pack P in-lane (vT key permutation makes PV A-frag in-lane)
    unsigned int uu[4][2];
    #pragma unroll
    for (int kt4 = 0; kt4 < 4; ++kt4) {
      asm("v_cvt_pk_bf16_f32 %0, %1, %2" : "=v"(uu[kt4][0]) : "v"(st[kt4][0]), "v"(st[kt4][1]));
      asm("v_cvt_pk_bf16_f32 %0, %1, %2" : "=v"(uu[kt4][1]) : "v"(st[kt4][2]), "v"(st[kt4][3]));
    }
    __builtin_amdgcn_s_setprio(1);
    #pragma unroll
    for (int kh = 0; kh < 2; ++kh) {
      union { unsigned int wrd[4]; bf16x8 v; } pfu;
      pfu.wrd[0] = uu[2 * kh][0];
      pfu.wrd[1] = uu[2 * kh][1];
      pfu.wrd[2] = uu[2 * kh + 1][0];
      pfu.wrd[3] = uu[2 * kh + 1][1];
      bf16x8 pf = pfu.v;
      #pragma unroll
      for (int dc = 0; dc < 6; ++dc) {
        bf16x8 vf = *reinterpret_cast<const bf16x8*>(&Sh[vbase + (dc * 16 + c) * 64 + ((kh * 32 + g * 8) ^ sw)]);
        acc[dc] = MFMA16(pf, vf, acc[dc]);
      }
    }
    __builtin_amdgcn_s_setprio(0);
  }
  // ---- in-block combine of the two key-halves ----
  __syncthreads();
  float* Cb = (float*)&Sh[0];            // [4][16][96] f32 = 24KB (overlays K0/V0)
  float* Ml = (float*)&Sh[12288];        // [4][16][2] f32 (overlays K1)
  if (sq == 1) {
    #pragma unroll
    for (int dc = 0; dc < 6; ++dc)
      #pragma unroll
      for (int i = 0; i < 4; ++i)
        Cb[(wq * 16 + g * 4 + i) * 96 + dc * 16 + c] = acc[dc][i];
    if (lane < 16) {
      Ml[(wq * 16 + lane) * 2]     = m;
      Ml[(wq * 16 + lane) * 2 + 1] = l;
    }
  }
  __syncthreads();
  if (sq == 0) {
    u16* ob = aout + (size_t)(b * 1024 + qt * 64 + wq * 16) * 768 + h * 96;
    #pragma unroll
    for (int i = 0; i < 4; ++i) {
      const int q = g * 4 + i;
      float m0q = __shfl(m, q), l0q = __shfl(l, q);
      float m1q = Ml[(wq * 16 + q) * 2], l1q = Ml[(wq * 16 + q) * 2 + 1];
      float M = fmaxf(m0q, m1q);
      float e0 = exp2a(m0q - M), e1 = exp2a(m1q - M);
      float inv = 1.f / (l0q * e0 + l1q * e1);
      #pragma unroll
      for (int dc = 0; dc < 6; ++dc) {
        float a1 = Cb[(wq * 16 + q) * 96 + dc * 16 + c];
        ob[(size_t)q * 768 + dc * 16 + c] = f2bf((acc[dc][i] * e0 + a1 * e1) * inv);
      }
    }
  }
}

extern "C" void kernel_launch(void* const* d_in, const int* in_sizes, int n_in,
                              void* d_out, int out_size, void* d_ws, size_t ws_size,
                              hipStream_t stream) {
  const float* hs     = (const float*)d_in[0];
  const float* qkv_w  = (const float*)d_in[1];
  const float* qkv_b  = (const float*)d_in[2];
  const float* proj_w = (const float*)d_in[3];
  const float* proj_b = (const float*)d_in[4];
  float* out = (float*)d_out;

  u16* hs_bf  = (u16*)d_ws;                 // 6291456 u16
  u16* qkvwT  = hs_bf  + 6291456;           // 884736
  u16* projwT = qkvwT  + 884736;            // 589824
  u16* vT     = projwT + 589824;            // 12582912 (32*96*4096)
  u16* kbuf   = vT     + 12582912;          // 12582912
  u16* spare  = kbuf   + 12582912;          // 12582912 (unused)
  u16* qpol   = spare  + 12582912;          // 3145728
  u16* aout   = qpol   + 3145728;           // 3145728

  prep<<<6504, 256, 0, stream>>>(hs, hs_bf, qkv_w, qkvwT, proj_w, projwT);

  gemm_bt<0, 128><<<2304, 256, 0, stream>>>(hs_bf, qkvwT, qkv_b,
                                            qpol, kbuf, vT, nullptr, 384, 18, 288);
  flash8<<<512, 512, 0, stream>>>(qpol, kbuf, vT, aout);
  gemm_bt<1, 64><<<384, 256, 0, stream>>>(aout, projwT, proj_b,
                                          nullptr, nullptr, nullptr, out, 768, 6, 48);
}